// Round 1
// baseline (3731.045 us; speedup 1.0000x reference)
//
#include <hip/hip_runtime.h>
#include <math.h>

#define B_ 8
#define C_ 256
#define S_ 9216
#define A_ 4
#define K_ 144
#define NB_ 64
#define XS 260   // LDS row stride (floats) for X tiles: odd multiple of 4 -> conflict-friendly

// ---------- transpose: xf[b][s][c] = in[b][c][s] ----------
__global__ __launch_bounds__(256) void t_kernel(const float* __restrict__ in,
                                                float* __restrict__ xf) {
  __shared__ float tile[32][33];
  int b = blockIdx.z;
  int c0 = blockIdx.y << 5, s0 = blockIdx.x << 5;
  int x = threadIdx.x & 31, y = threadIdx.x >> 5;  // 32 x 8
  const float* ip = in + ((size_t)b * C_ + c0 + y) * S_ + s0 + x;
#pragma unroll
  for (int k = 0; k < 32; k += 8) tile[y + k][x] = ip[(size_t)k * S_];
  __syncthreads();
  float* op = xf + ((size_t)b * S_ + s0 + y) * C_ + c0 + x;
#pragma unroll
  for (int k = 0; k < 32; k += 8) op[(size_t)k * C_] = tile[x][y + k];
}

// ---------- hash: fp64 projection + max over m=64 columns (lane = column) ----------
__global__ __launch_bounds__(256) void hash_kernel(const float* __restrict__ xf,
                                                   const float* __restrict__ in,
                                                   const float* __restrict__ RM,
                                                   unsigned long long* __restrict__ keys,
                                                   int use_xf) {
  __shared__ double Rld[C_ * 64];  // 128 KiB: R[a] as fp64
  int b = blockIdx.x / (S_ / 128);
  int s0 = (blockIdx.x % (S_ / 128)) * 128;
  int tid = threadIdx.x;
  int w = __builtin_amdgcn_readfirstlane(tid >> 6);
  int lane = tid & 63;
  for (int a = 0; a < A_; ++a) {
    __syncthreads();
    for (int e = tid; e < C_ * 64; e += 256) Rld[e] = (double)RM[a * C_ * 64 + e];
    __syncthreads();
    unsigned long long* kb = keys + ((size_t)(b * A_ + a)) * S_;
    for (int t = 0; t < 8; ++t) {
      int sb = s0 + w * 32 + t * 4;
      const float* x0;
      size_t cs, rs;
      if (use_xf) { x0 = xf + ((size_t)b * S_ + sb) * C_; cs = 1;  rs = C_; }
      else        { x0 = in + (size_t)b * C_ * S_ + sb;   cs = S_; rs = 1;  }
      double a0 = 0, a1 = 0, a2 = 0, a3 = 0;
#pragma unroll 4
      for (int c = 0; c < C_; ++c) {
        double rv = Rld[c * 64 + lane];
        size_t o = (size_t)c * cs;
        a0 = fma((double)x0[o], rv, a0);
        a1 = fma((double)x0[o + rs], rv, a1);
        a2 = fma((double)x0[o + 2 * rs], rv, a2);
        a3 = fma((double)x0[o + 3 * rs], rv, a3);
      }
      double av[4] = {a0, a1, a2, a3};
#pragma unroll
      for (int q = 0; q < 4; ++q) {
        double m = av[q];
        for (int off = 32; off; off >>= 1) {
          double o = __shfl_xor(m, off);
          m = m > o ? m : o;
        }
        if (lane == 0) {
          unsigned long long u = (unsigned long long)__double_as_longlong(m);
          unsigned long long mono = u ^ ((u >> 63) ? ~0ull : 0x8000000000000000ull);
          // ascending key == descending hash; low 14 bits carry the position
          kb[sb + q] = (~mono & ~0x3FFFull) | (unsigned long long)(sb + q);
        }
      }
    }
  }
}

// ---------- bitonic sort of 16384 uint64 keys in LDS, per (b,a) ----------
__global__ __launch_bounds__(1024) void sort_kernel(const unsigned long long* __restrict__ keys,
                                                    int* __restrict__ idxs) {
  __shared__ unsigned long long lk[16384];  // 128 KiB
  int tid = threadIdx.x;
  const unsigned long long* kb = keys + (size_t)blockIdx.x * S_;
  for (int i = tid; i < 16384; i += 1024) lk[i] = (i < S_) ? kb[i] : ~0ull;
  for (int k = 2; k <= 16384; k <<= 1)
    for (int j = k >> 1; j > 0; j >>= 1) {
      __syncthreads();
      for (int i = tid; i < 16384; i += 1024) {
        int l = i ^ j;
        if (l > i) {
          unsigned long long a = lk[i], bv = lk[l];
          bool sw = ((i & k) == 0) ? (a > bv) : (a < bv);
          if (sw) { lk[i] = bv; lk[l] = a; }
        }
      }
    }
  __syncthreads();
  int* ob = idxs + (size_t)blockIdx.x * S_;
  for (int i = tid; i < S_; i += 1024) ob[i] = (int)(lk[i] & 0x3FFFull);
}

// ---------- per-bucket attention (fp32), scatter back by idx ----------
__global__ __launch_bounds__(256) void attn_kernel(const float* __restrict__ xf,
                                                   const float* __restrict__ in,
                                                   const int* __restrict__ idxs,
                                                   float* __restrict__ outacc,
                                                   float* __restrict__ out,
                                                   int use_xf, int path_a) {
  __shared__ float X[K_ * XS];       // 149,760 B
  __shared__ float Pt[4][K_ * 4];    //   9,216 B  (per-wave probs, transposed [j][row])
  int blk = blockIdx.x;
  int r = blk & 63, a = (blk >> 6) & 3, b = blk >> 8;
  int tid = threadIdx.x;
  const int* __restrict__ idxr = idxs + ((size_t)(b * A_ + a)) * S_ + r * K_;
  if (use_xf) {
    for (int e = tid; e < K_ * 64; e += 256) {
      int i = e >> 6, q = (e & 63) << 2;
      int s = idxr[i];
      float4 v = *(const float4*)(xf + ((size_t)b * S_ + s) * C_ + q);
      *(float4*)(X + i * XS + q) = v;
    }
  } else {
    for (int e = tid; e < K_ * C_; e += 256) {
      int i = e >> 8, c = e & 255;
      int s = idxr[i];
      X[i * XS + c] = in[((size_t)b * C_ + c) * S_ + s];
    }
  }
  __syncthreads();
  int w = __builtin_amdgcn_readfirstlane(tid >> 6);
  int lane = tid & 63;
  bool has2 = lane < 16;
  int j0 = lane, j1 = lane + 64, j2 = has2 ? lane + 128 : lane;
  float* Pw = Pt[w];
  const float scale = 0.0625f;  // 1/sqrt(256)
  for (int g = 0; g < 9; ++g) {
    int i0 = w * 36 + g * 4;  // this wave's 4 rows
    float acc[4][3] = {};
#pragma unroll 2
    for (int c4 = 0; c4 < 64; ++c4) {
      int cw = c4 << 2;
      float4 b0 = *(const float4*)(X + j0 * XS + cw);
      float4 b1 = *(const float4*)(X + j1 * XS + cw);
      float4 b2 = *(const float4*)(X + j2 * XS + cw);
#pragma unroll
      for (int rr = 0; rr < 4; ++rr) {
        float4 av = *(const float4*)(X + (i0 + rr) * XS + cw);  // broadcast
        acc[rr][0] += av.x * b0.x + av.y * b0.y + av.z * b0.z + av.w * b0.w;
        acc[rr][1] += av.x * b1.x + av.y * b1.y + av.z * b1.z + av.w * b1.w;
        acc[rr][2] += av.x * b2.x + av.y * b2.y + av.z * b2.z + av.w * b2.w;
      }
    }
#pragma unroll
    for (int rr = 0; rr < 4; ++rr) {
      float s0 = acc[rr][0] * scale;
      float s1 = acc[rr][1] * scale;
      float s2 = has2 ? acc[rr][2] * scale : -1e30f;
      float mx = fmaxf(fmaxf(s0, s1), s2);
      for (int off = 32; off; off >>= 1) mx = fmaxf(mx, __shfl_xor(mx, off));
      float e0 = __expf(s0 - mx), e1 = __expf(s1 - mx);
      float e2 = has2 ? __expf(s2 - mx) : 0.f;
      float sm = e0 + e1 + e2;
      for (int off = 32; off; off >>= 1) sm += __shfl_xor(sm, off);
      float inv = 1.0f / sm;
      Pw[j0 * 4 + rr] = e0 * inv;
      Pw[j1 * 4 + rr] = e1 * inv;
      if (has2) Pw[j2 * 4 + rr] = e2 * inv;
    }
    // PV: lane owns c-quad (lane*4), 4 rows at once
    float o[4][4] = {};
    int cw = lane << 2;
#pragma unroll 4
    for (int j = 0; j < K_; ++j) {
      float4 xr = *(const float4*)(X + j * XS + cw);
      float4 p = *(const float4*)(Pw + j * 4);  // broadcast
      o[0][0] += p.x * xr.x; o[0][1] += p.x * xr.y; o[0][2] += p.x * xr.z; o[0][3] += p.x * xr.w;
      o[1][0] += p.y * xr.x; o[1][1] += p.y * xr.y; o[1][2] += p.y * xr.z; o[1][3] += p.y * xr.w;
      o[2][0] += p.z * xr.x; o[2][1] += p.z * xr.y; o[2][2] += p.z * xr.z; o[2][3] += p.z * xr.w;
      o[3][0] += p.w * xr.x; o[3][1] += p.w * xr.y; o[3][2] += p.w * xr.z; o[3][3] += p.w * xr.w;
    }
#pragma unroll
    for (int rr = 0; rr < 4; ++rr) {
      int s = idxr[i0 + rr];
      if (path_a) {
        float4 v = make_float4(o[rr][0], o[rr][1], o[rr][2], o[rr][3]);
        *(float4*)(outacc + (((size_t)(b * A_ + a)) * S_ + s) * C_ + cw) = v;
      } else {
        float* dst = out + ((size_t)b * S_ + s) * C_ + cw;
        atomicAdd(dst + 0, o[rr][0] * 0.25f);
        atomicAdd(dst + 1, o[rr][1] * 0.25f);
        atomicAdd(dst + 2, o[rr][2] * 0.25f);
        atomicAdd(dst + 3, o[rr][3] * 0.25f);
      }
    }
  }
}

// ---------- average over rounds ----------
__global__ __launch_bounds__(256) void reduce_kernel(const float* __restrict__ acc,
                                                     float* __restrict__ out) {
  size_t i = (size_t)blockIdx.x * 256 + threadIdx.x;
  size_t n4 = (size_t)B_ * S_ * C_ / 4;
  if (i >= n4) return;
  size_t f = i * 4;
  size_t per_b = (size_t)S_ * C_;
  size_t b = f / per_b, o = f - b * per_b;
  const float* base = acc + (b * A_) * per_b + o;
  float4 v0 = *(const float4*)(base);
  float4 v1 = *(const float4*)(base + per_b);
  float4 v2 = *(const float4*)(base + 2 * per_b);
  float4 v3 = *(const float4*)(base + 3 * per_b);
  float4 rv = make_float4((v0.x + v1.x + v2.x + v3.x) * 0.25f,
                          (v0.y + v1.y + v2.y + v3.y) * 0.25f,
                          (v0.z + v1.z + v2.z + v3.z) * 0.25f,
                          (v0.w + v1.w + v2.w + v3.w) * 0.25f);
  *(float4*)(out + f) = rv;
}

__global__ __launch_bounds__(256) void zero_kernel(float* __restrict__ out) {
  size_t i = (size_t)blockIdx.x * 256 + threadIdx.x;
  size_t n4 = (size_t)B_ * S_ * C_ / 4;
  if (i >= n4) return;
  *(float4*)(out + i * 4) = make_float4(0.f, 0.f, 0.f, 0.f);
}

extern "C" void kernel_launch(void* const* d_in, const int* in_sizes, int n_in,
                              void* d_out, int out_size, void* d_ws, size_t ws_size,
                              hipStream_t stream) {
  const float* in = (const float*)d_in[0];
  const float* RM = (const float*)d_in[1];
  float* out = (float*)d_out;
  const size_t xf_b  = (size_t)B_ * S_ * C_ * 4;        //  75.5 MB
  const size_t key_b = (size_t)B_ * A_ * S_ * 8;        //   2.36 MB
  const size_t idx_b = (size_t)B_ * A_ * S_ * 4;        //   1.18 MB
  const size_t acc_b = (size_t)B_ * A_ * S_ * C_ * 4;   // 302 MB
  char* ws = (char*)d_ws;
  int use_xf = ws_size >= xf_b + key_b + idx_b;
  int path_a = ws_size >= xf_b + key_b + idx_b + acc_b;
  size_t off = 0;
  float* xf = nullptr;
  if (use_xf) { xf = (float*)(ws + off); off += xf_b; }
  unsigned long long* keys = (unsigned long long*)(ws + off); off += key_b;
  int* idxs = (int*)(ws + off); off += idx_b;
  float* outacc = nullptr;
  if (path_a) { outacc = (float*)(ws + off); off += acc_b; }

  if (use_xf)
    t_kernel<<<dim3(S_ / 32, C_ / 32, B_), 256, 0, stream>>>(in, xf);
  hash_kernel<<<dim3(B_ * (S_ / 128)), 256, 0, stream>>>(xf, in, RM, keys, use_xf);
  sort_kernel<<<dim3(B_ * A_), 1024, 0, stream>>>(keys, idxs);
  size_t n4 = (size_t)B_ * S_ * C_ / 4;
  int rb = (int)((n4 + 255) / 256);
  if (!path_a) zero_kernel<<<dim3(rb), 256, 0, stream>>>(out);
  attn_kernel<<<dim3(B_ * A_ * NB_), 256, 0, stream>>>(xf, in, idxs, outacc, out, use_xf, path_a);
  if (path_a) reduce_kernel<<<dim3(rb), 256, 0, stream>>>(outacc, out);
}

// Round 2
// 2187.865 us; speedup vs baseline: 1.7053x; 1.7053x over previous
//
#include <hip/hip_runtime.h>
#include <math.h>

#define B_ 8
#define C_ 256
#define S_ 9216
#define A_ 4
#define K_ 144
#define NB_ 64
#define XS 260   // LDS row stride (floats) for X tiles: odd multiple of 4 -> conflict-friendly
#define MCH 16   // hash m-chunk per pass (acc = 32 VGPRs fp64)

// ---------- transpose: xf[b][s][c] = in[b][c][s] ----------
__global__ __launch_bounds__(256) void t_kernel(const float* __restrict__ in,
                                                float* __restrict__ xf) {
  __shared__ float tile[32][33];
  int b = blockIdx.z;
  int c0 = blockIdx.y << 5, s0 = blockIdx.x << 5;
  int x = threadIdx.x & 31, y = threadIdx.x >> 5;  // 32 x 8
  const float* ip = in + ((size_t)b * C_ + c0 + y) * S_ + s0 + x;
#pragma unroll
  for (int k = 0; k < 32; k += 8) tile[y + k][x] = ip[(size_t)k * S_];
  __syncthreads();
  float* op = xf + ((size_t)b * S_ + s0 + y) * C_ + c0 + x;
#pragma unroll
  for (int k = 0; k < 32; k += 8) op[(size_t)k * C_] = tile[x][y + k];
}

// ---------- R fp32 -> fp64 once ----------
__global__ __launch_bounds__(256) void cvt_r_kernel(const float* __restrict__ RM,
                                                    double* __restrict__ R64) {
  int i = blockIdx.x * 256 + threadIdx.x;
  if (i < A_ * C_ * 64) R64[i] = (double)RM[i];
}

// ---------- hash: thread = (b,a,s); fp64 FMA with SGPR-resident R ----------
__global__ __launch_bounds__(256) void hash_kernel(const float* __restrict__ in,
                                                   const double* __restrict__ R64,
                                                   unsigned long long* __restrict__ keys) {
  int blk = blockIdx.x;  // (b, a, s-chunk)
  int chunk = blk % (S_ / 256);
  int a = (blk / (S_ / 256)) % A_;
  int b = blk / (S_ / 256) / A_;
  int s = chunk * 256 + threadIdx.x;
  const float* __restrict__ xb = in + (size_t)b * C_ * S_ + s;
  const double* __restrict__ Rb = R64 + (size_t)a * C_ * 64;
  double hmax = -1e300;
  for (int mp = 0; mp < 64; mp += MCH) {
    double acc[MCH];
#pragma unroll
    for (int i = 0; i < MCH; ++i) acc[i] = 0.0;
#pragma unroll 2
    for (int c = 0; c < C_; ++c) {
      double xv = (double)xb[(size_t)c * S_];
      const double* __restrict__ Rc = Rb + c * 64 + mp;  // wave-uniform -> s_load
#pragma unroll
      for (int i = 0; i < MCH; ++i) acc[i] = fma(xv, Rc[i], acc[i]);
    }
#pragma unroll
    for (int i = 0; i < MCH; ++i) hmax = hmax > acc[i] ? hmax : acc[i];
  }
  unsigned long long u = (unsigned long long)__double_as_longlong(hmax);
  unsigned long long mono = u ^ ((u >> 63) ? ~0ull : 0x8000000000000000ull);
  // ascending key == descending hash; low 14 bits carry the position
  keys[((size_t)(b * A_ + a)) * S_ + s] = (~mono & ~0x3FFFull) | (unsigned long long)s;
}

// ---------- bitonic sort of 16384 uint64 keys in LDS, per (b,a) ----------
__global__ __launch_bounds__(1024) void sort_kernel(const unsigned long long* __restrict__ keys,
                                                    int* __restrict__ idxs) {
  __shared__ unsigned long long lk[16384];  // 128 KiB
  int tid = threadIdx.x;
  const unsigned long long* kb = keys + (size_t)blockIdx.x * S_;
  for (int i = tid; i < 16384; i += 1024) lk[i] = (i < S_) ? kb[i] : ~0ull;
  for (int k = 2; k <= 16384; k <<= 1)
    for (int j = k >> 1; j > 0; j >>= 1) {
      __syncthreads();
      for (int i = tid; i < 16384; i += 1024) {
        int l = i ^ j;
        if (l > i) {
          unsigned long long a = lk[i], bv = lk[l];
          bool sw = ((i & k) == 0) ? (a > bv) : (a < bv);
          if (sw) { lk[i] = bv; lk[l] = a; }
        }
      }
    }
  __syncthreads();
  int* ob = idxs + (size_t)blockIdx.x * S_;
  for (int i = tid; i < S_; i += 1024) ob[i] = (int)(lk[i] & 0x3FFFull);
}

// ---------- per-bucket attention (fp32), scatter back by idx ----------
__global__ __launch_bounds__(256) void attn_kernel(const float* __restrict__ xf,
                                                   const float* __restrict__ in,
                                                   const int* __restrict__ idxs,
                                                   float* __restrict__ outacc,
                                                   float* __restrict__ out,
                                                   int use_xf, int path_a) {
  __shared__ float X[K_ * XS];       // 149,760 B
  __shared__ float Pt[4][K_ * 4];    //   9,216 B  (per-wave probs, transposed [j][row])
  int blk = blockIdx.x;
  int r = blk & 63, a = (blk >> 6) & 3, b = blk >> 8;
  int tid = threadIdx.x;
  const int* __restrict__ idxr = idxs + ((size_t)(b * A_ + a)) * S_ + r * K_;
  if (use_xf) {
    for (int e = tid; e < K_ * 64; e += 256) {
      int i = e >> 6, q = (e & 63) << 2;
      int s = idxr[i];
      float4 v = *(const float4*)(xf + ((size_t)b * S_ + s) * C_ + q);
      *(float4*)(X + i * XS + q) = v;
    }
  } else {
    for (int e = tid; e < K_ * C_; e += 256) {
      int i = e >> 8, c = e & 255;
      int s = idxr[i];
      X[i * XS + c] = in[((size_t)b * C_ + c) * S_ + s];
    }
  }
  __syncthreads();
  int w = __builtin_amdgcn_readfirstlane(tid >> 6);
  int lane = tid & 63;
  bool has2 = lane < 16;
  int j0 = lane, j1 = lane + 64, j2 = has2 ? lane + 128 : lane;
  float* Pw = Pt[w];
  const float scale = 0.0625f;  // 1/sqrt(256)
  for (int g = 0; g < 9; ++g) {
    int i0 = w * 36 + g * 4;  // this wave's 4 rows
    float acc[4][3] = {};
#pragma unroll 2
    for (int c4 = 0; c4 < 64; ++c4) {
      int cw = c4 << 2;
      float4 b0 = *(const float4*)(X + j0 * XS + cw);
      float4 b1 = *(const float4*)(X + j1 * XS + cw);
      float4 b2 = *(const float4*)(X + j2 * XS + cw);
#pragma unroll
      for (int rr = 0; rr < 4; ++rr) {
        float4 av = *(const float4*)(X + (i0 + rr) * XS + cw);  // broadcast
        acc[rr][0] += av.x * b0.x + av.y * b0.y + av.z * b0.z + av.w * b0.w;
        acc[rr][1] += av.x * b1.x + av.y * b1.y + av.z * b1.z + av.w * b1.w;
        acc[rr][2] += av.x * b2.x + av.y * b2.y + av.z * b2.z + av.w * b2.w;
      }
    }
#pragma unroll
    for (int rr = 0; rr < 4; ++rr) {
      float s0 = acc[rr][0] * scale;
      float s1 = acc[rr][1] * scale;
      float s2 = has2 ? acc[rr][2] * scale : -1e30f;
      float mx = fmaxf(fmaxf(s0, s1), s2);
      for (int off = 32; off; off >>= 1) mx = fmaxf(mx, __shfl_xor(mx, off));
      float e0 = __expf(s0 - mx), e1 = __expf(s1 - mx);
      float e2 = has2 ? __expf(s2 - mx) : 0.f;
      float sm = e0 + e1 + e2;
      for (int off = 32; off; off >>= 1) sm += __shfl_xor(sm, off);
      float inv = 1.0f / sm;
      Pw[j0 * 4 + rr] = e0 * inv;
      Pw[j1 * 4 + rr] = e1 * inv;
      if (has2) Pw[j2 * 4 + rr] = e2 * inv;
    }
    // PV: lane owns c-quad (lane*4), 4 rows at once
    float o[4][4] = {};
    int cw = lane << 2;
#pragma unroll 4
    for (int j = 0; j < K_; ++j) {
      float4 xr = *(const float4*)(X + j * XS + cw);
      float4 p = *(const float4*)(Pw + j * 4);  // broadcast
      o[0][0] += p.x * xr.x; o[0][1] += p.x * xr.y; o[0][2] += p.x * xr.z; o[0][3] += p.x * xr.w;
      o[1][0] += p.y * xr.x; o[1][1] += p.y * xr.y; o[1][2] += p.y * xr.z; o[1][3] += p.y * xr.w;
      o[2][0] += p.z * xr.x; o[2][1] += p.z * xr.y; o[2][2] += p.z * xr.z; o[2][3] += p.z * xr.w;
      o[3][0] += p.w * xr.x; o[3][1] += p.w * xr.y; o[3][2] += p.w * xr.z; o[3][3] += p.w * xr.w;
    }
#pragma unroll
    for (int rr = 0; rr < 4; ++rr) {
      int s = idxr[i0 + rr];
      if (path_a) {
        float4 v = make_float4(o[rr][0], o[rr][1], o[rr][2], o[rr][3]);
        *(float4*)(outacc + (((size_t)(b * A_ + a)) * S_ + s) * C_ + cw) = v;
      } else {
        float* dst = out + ((size_t)b * S_ + s) * C_ + cw;
        atomicAdd(dst + 0, o[rr][0] * 0.25f);
        atomicAdd(dst + 1, o[rr][1] * 0.25f);
        atomicAdd(dst + 2, o[rr][2] * 0.25f);
        atomicAdd(dst + 3, o[rr][3] * 0.25f);
      }
    }
  }
}

// ---------- average over rounds ----------
__global__ __launch_bounds__(256) void reduce_kernel(const float* __restrict__ acc,
                                                     float* __restrict__ out) {
  size_t i = (size_t)blockIdx.x * 256 + threadIdx.x;
  size_t n4 = (size_t)B_ * S_ * C_ / 4;
  if (i >= n4) return;
  size_t f = i * 4;
  size_t per_b = (size_t)S_ * C_;
  size_t b = f / per_b, o = f - b * per_b;
  const float* base = acc + (b * A_) * per_b + o;
  float4 v0 = *(const float4*)(base);
  float4 v1 = *(const float4*)(base + per_b);
  float4 v2 = *(const float4*)(base + 2 * per_b);
  float4 v3 = *(const float4*)(base + 3 * per_b);
  float4 rv = make_float4((v0.x + v1.x + v2.x + v3.x) * 0.25f,
                          (v0.y + v1.y + v2.y + v3.y) * 0.25f,
                          (v0.z + v1.z + v2.z + v3.z) * 0.25f,
                          (v0.w + v1.w + v2.w + v3.w) * 0.25f);
  *(float4*)(out + f) = rv;
}

__global__ __launch_bounds__(256) void zero_kernel(float* __restrict__ out) {
  size_t i = (size_t)blockIdx.x * 256 + threadIdx.x;
  size_t n4 = (size_t)B_ * S_ * C_ / 4;
  if (i >= n4) return;
  *(float4*)(out + i * 4) = make_float4(0.f, 0.f, 0.f, 0.f);
}

extern "C" void kernel_launch(void* const* d_in, const int* in_sizes, int n_in,
                              void* d_out, int out_size, void* d_ws, size_t ws_size,
                              hipStream_t stream) {
  const float* in = (const float*)d_in[0];
  const float* RM = (const float*)d_in[1];
  float* out = (float*)d_out;
  const size_t r64_b = (size_t)A_ * C_ * 64 * 8;        //   0.5 MB
  const size_t key_b = (size_t)B_ * A_ * S_ * 8;        //   2.36 MB
  const size_t idx_b = (size_t)B_ * A_ * S_ * 4;        //   1.18 MB
  const size_t xf_b  = (size_t)B_ * S_ * C_ * 4;        //  75.5 MB
  const size_t acc_b = (size_t)B_ * A_ * S_ * C_ * 4;   // 302 MB
  char* ws = (char*)d_ws;
  size_t off = 0;
  double* R64 = (double*)(ws + off); off += r64_b;
  unsigned long long* keys = (unsigned long long*)(ws + off); off += key_b;
  int* idxs = (int*)(ws + off); off += idx_b;
  int use_xf = ws_size >= off + xf_b;
  float* xf = nullptr;
  if (use_xf) { xf = (float*)(ws + off); off += xf_b; }
  int path_a = ws_size >= off + acc_b;
  float* outacc = nullptr;
  if (path_a) { outacc = (float*)(ws + off); off += acc_b; }

  cvt_r_kernel<<<dim3((A_ * C_ * 64 + 255) / 256), 256, 0, stream>>>(RM, R64);
  if (use_xf)
    t_kernel<<<dim3(S_ / 32, C_ / 32, B_), 256, 0, stream>>>(in, xf);
  hash_kernel<<<dim3(B_ * A_ * (S_ / 256)), 256, 0, stream>>>(in, R64, keys);
  sort_kernel<<<dim3(B_ * A_), 1024, 0, stream>>>(keys, idxs);
  size_t n4 = (size_t)B_ * S_ * C_ / 4;
  int rb = (int)((n4 + 255) / 256);
  if (!path_a) zero_kernel<<<dim3(rb), 256, 0, stream>>>(out);
  attn_kernel<<<dim3(B_ * A_ * NB_), 256, 0, stream>>>(xf, in, idxs, outacc, out, use_xf, path_a);
  if (path_a) reduce_kernel<<<dim3(rb), 256, 0, stream>>>(outacc, out);
}

// Round 3
// 1187.453 us; speedup vs baseline: 3.1421x; 1.8425x over previous
//
#include <hip/hip_runtime.h>
#include <math.h>

#define B_ 8
#define C_ 256
#define S_ 9216
#define A_ 4
#define K_ 144
#define NB_ 64
#define MCH 16   // hash m-chunk per pass (acc = 32 VGPRs fp64)

typedef __bf16 bf16x8 __attribute__((ext_vector_type(8)));
typedef float f32x4 __attribute__((ext_vector_type(4)));
#define MFMA(a, b, c) __builtin_amdgcn_mfma_f32_16x16x32_bf16(a, b, c, 0, 0, 0)

// bf16 round-to-nearest-even
__device__ __forceinline__ unsigned short f2bf(float f) {
  unsigned int u = __float_as_uint(f);
  u = (u + 0x7FFFu + ((u >> 16) & 1u)) >> 16;
  return (unsigned short)u;
}

// ---------- transpose: xf[b][s][c] = in[b][c][s] ----------
__global__ __launch_bounds__(256) void t_kernel(const float* __restrict__ in,
                                                float* __restrict__ xf) {
  __shared__ float tile[32][33];
  int b = blockIdx.z;
  int c0 = blockIdx.y << 5, s0 = blockIdx.x << 5;
  int x = threadIdx.x & 31, y = threadIdx.x >> 5;  // 32 x 8
  const float* ip = in + ((size_t)b * C_ + c0 + y) * S_ + s0 + x;
#pragma unroll
  for (int k = 0; k < 32; k += 8) tile[y + k][x] = ip[(size_t)k * S_];
  __syncthreads();
  float* op = xf + ((size_t)b * S_ + s0 + y) * C_ + c0 + x;
#pragma unroll
  for (int k = 0; k < 32; k += 8) op[(size_t)k * C_] = tile[x][y + k];
}

// ---------- R fp32 -> fp64 once ----------
__global__ __launch_bounds__(256) void cvt_r_kernel(const float* __restrict__ RM,
                                                    double* __restrict__ R64) {
  int i = blockIdx.x * 256 + threadIdx.x;
  if (i < A_ * C_ * 64) R64[i] = (double)RM[i];
}

// ---------- hash: thread = (b,a,s); fp64 FMA with SGPR-resident R ----------
__global__ __launch_bounds__(256) void hash_kernel(const float* __restrict__ in,
                                                   const double* __restrict__ R64,
                                                   unsigned long long* __restrict__ keys) {
  int blk = blockIdx.x;  // (b, a, s-chunk)
  int chunk = blk % (S_ / 256);
  int a = (blk / (S_ / 256)) % A_;
  int b = blk / (S_ / 256) / A_;
  int s = chunk * 256 + threadIdx.x;
  const float* __restrict__ xb = in + (size_t)b * C_ * S_ + s;
  const double* __restrict__ Rb = R64 + (size_t)a * C_ * 64;
  double hmax = -1e300;
  for (int mp = 0; mp < 64; mp += MCH) {
    double acc[MCH];
#pragma unroll
    for (int i = 0; i < MCH; ++i) acc[i] = 0.0;
#pragma unroll 2
    for (int c = 0; c < C_; ++c) {
      double xv = (double)xb[(size_t)c * S_];
      const double* __restrict__ Rc = Rb + c * 64 + mp;  // wave-uniform -> s_load
#pragma unroll
      for (int i = 0; i < MCH; ++i) acc[i] = fma(xv, Rc[i], acc[i]);
    }
#pragma unroll
    for (int i = 0; i < MCH; ++i) hmax = hmax > acc[i] ? hmax : acc[i];
  }
  unsigned long long u = (unsigned long long)__double_as_longlong(hmax);
  unsigned long long mono = u ^ ((u >> 63) ? ~0ull : 0x8000000000000000ull);
  keys[((size_t)(b * A_ + a)) * S_ + s] = (~mono & ~0x3FFFull) | (unsigned long long)s;
}

// ---------- bitonic sort of 16384 uint64 keys in LDS, per (b,a) ----------
__global__ __launch_bounds__(1024) void sort_kernel(const unsigned long long* __restrict__ keys,
                                                    int* __restrict__ idxs) {
  __shared__ unsigned long long lk[16384];  // 128 KiB
  int tid = threadIdx.x;
  const unsigned long long* kb = keys + (size_t)blockIdx.x * S_;
  for (int i = tid; i < 16384; i += 1024) lk[i] = (i < S_) ? kb[i] : ~0ull;
  for (int k = 2; k <= 16384; k <<= 1)
    for (int j = k >> 1; j > 0; j >>= 1) {
      __syncthreads();
      for (int i = tid; i < 16384; i += 1024) {
        int l = i ^ j;
        if (l > i) {
          unsigned long long a = lk[i], bv = lk[l];
          bool sw = ((i & k) == 0) ? (a > bv) : (a < bv);
          if (sw) { lk[i] = bv; lk[l] = a; }
        }
      }
    }
  __syncthreads();
  int* ob = idxs + (size_t)blockIdx.x * S_;
  for (int i = tid; i < S_; i += 1024) ob[i] = (int)(lk[i] & 0x3FFFull);
}

// ---------- per-bucket MFMA attention (bf16 in, fp32 accum) ----------
// LDS: Xh [144][256] bf16, swz ^((row&7)<<3) on ushort idx   -> 73728 B
//      XT [128][160] bf16 half-c transposed, swz ^((c&7)<<3) -> 40960 B
//      Ps [144][168] bf16 probs, cols 144..167 zeroed        -> 48384 B
__global__ __launch_bounds__(256, 1) void attn_kernel(const float* __restrict__ xf,
                                                      const float* __restrict__ in,
                                                      const int* __restrict__ idxs,
                                                      float* __restrict__ outacc,
                                                      float* __restrict__ out,
                                                      int use_xf, int path_a) {
  __shared__ __align__(16) unsigned short Xh[K_ * 256];   // 73728 B
  __shared__ __align__(16) unsigned short XT[128 * 160];  // 40960 B
  __shared__ __align__(16) unsigned short Ps[K_ * 168];   // 48384 B
  int blk = blockIdx.x;
  int r = blk & 63, a = (blk >> 6) & 3, b = blk >> 8;
  int tid = threadIdx.x;
  int w = __builtin_amdgcn_readfirstlane(tid >> 6);
  int lane = tid & 63;
  int lr = lane & 15, lg = lane >> 4;
  const int* __restrict__ idxr = idxs + ((size_t)(b * A_ + a)) * S_ + r * K_;
  const float* __restrict__ xfb = xf + (size_t)b * S_ * C_;

  // ---- stage Xh (all threads) ----
  if (use_xf) {
    for (int e = tid; e < K_ * 64; e += 256) {
      int i = e >> 6, q = (e & 63) << 2;
      int s = idxr[i];
      float4 v = *(const float4*)(xfb + (size_t)s * C_ + q);
      unsigned int lo = (unsigned int)f2bf(v.x) | ((unsigned int)f2bf(v.y) << 16);
      unsigned int hi = (unsigned int)f2bf(v.z) | ((unsigned int)f2bf(v.w) << 16);
      int idx = (i * 256 + q) ^ ((i & 7) << 3);
      *(uint2*)&Xh[idx] = make_uint2(lo, hi);
    }
  } else {
    for (int e = tid; e < K_ * C_; e += 256) {
      int i = e >> 8, c = e & 255;
      Xh[(i * 256 + c) ^ ((i & 7) << 3)] =
          f2bf(in[((size_t)b * C_ + c) * S_ + idxr[i]]);
    }
  }
  __syncthreads();

  f32x4 acc[3][9];
  if (w < 3) {
    // ---- QK^T: wave w owns i-tiles {w*3 .. w*3+2} ----
    int it0 = w * 3;
#pragma unroll
    for (int q = 0; q < 3; ++q)
#pragma unroll
      for (int jt = 0; jt < 9; ++jt) acc[q][jt] = (f32x4){0.f, 0.f, 0.f, 0.f};
    for (int kt = 0; kt < 8; ++kt) {
      int c0 = kt * 32 + lg * 8;
      bf16x8 fr[9];
#pragma unroll
      for (int jt = 0; jt < 9; ++jt) {
        int row = jt * 16 + lr;
        fr[jt] = *(const bf16x8*)&Xh[(row * 256 + c0) ^ ((row & 7) << 3)];
      }
#pragma unroll
      for (int q = 0; q < 3; ++q)
#pragma unroll
        for (int jt = 0; jt < 9; ++jt)
          acc[q][jt] = MFMA(fr[it0 + q], fr[jt], acc[q][jt]);
    }
    // ---- softmax along j (all 9 tiles in-wave), write P to LDS ----
#pragma unroll
    for (int q = 0; q < 3; ++q) {
#pragma unroll
      for (int rr = 0; rr < 4; ++rr) {
        float m = -1e30f;
#pragma unroll
        for (int jt = 0; jt < 9; ++jt) m = fmaxf(m, acc[q][jt][rr]);
        m = fmaxf(m, __shfl_xor(m, 1));
        m = fmaxf(m, __shfl_xor(m, 2));
        m = fmaxf(m, __shfl_xor(m, 4));
        m = fmaxf(m, __shfl_xor(m, 8));
        float sum = 0.f;
#pragma unroll
        for (int jt = 0; jt < 9; ++jt) {
          float e = __expf((acc[q][jt][rr] - m) * 0.0625f);
          acc[q][jt][rr] = e;
          sum += e;
        }
        sum += __shfl_xor(sum, 1);
        sum += __shfl_xor(sum, 2);
        sum += __shfl_xor(sum, 4);
        sum += __shfl_xor(sum, 8);
        float inv = 1.0f / sum;
        int row_i = (it0 + q) * 16 + lg * 4 + rr;
#pragma unroll
        for (int jt = 0; jt < 9; ++jt)
          Ps[row_i * 168 + jt * 16 + lr] = f2bf(acc[q][jt][rr] * inv);
      }
    }
  } else {
    // ---- wave 3: zero pads + stage XT half 0 ----
    for (int e = lane; e < K_ * 24; e += 64) {
      int i = e / 24, j = 144 + e % 24;
      Ps[i * 168 + j] = 0;
    }
    for (int e = lane; e < 128 * 16; e += 64) {
      int c = e >> 4, j = 144 + (e & 15);
      XT[(c * 160 + j) ^ ((c & 7) << 3)] = 0;
    }
    if (use_xf) {
      for (int it = 0; it < 72; ++it) {
        int j = it * 2 + (lane >> 5), qq = lane & 31;
        int s = idxr[j];
        float4 v = *(const float4*)(xfb + (size_t)s * C_ + qq * 4);
        int c = qq * 4;
        XT[(c * 160 + j) ^ ((c & 7) << 3)] = f2bf(v.x);
        XT[((c + 1) * 160 + j) ^ (((c + 1) & 7) << 3)] = f2bf(v.y);
        XT[((c + 2) * 160 + j) ^ (((c + 2) & 7) << 3)] = f2bf(v.z);
        XT[((c + 3) * 160 + j) ^ (((c + 3) & 7) << 3)] = f2bf(v.w);
      }
    } else {
      for (int c = 0; c < 128; ++c)
        for (int j = lane; j < K_; j += 64)
          XT[(c * 160 + j) ^ ((c & 7) << 3)] =
              f2bf(in[((size_t)b * C_ + c) * S_ + idxr[j]]);
    }
  }
  __syncthreads();

  // ---- PV over c-half h: all 4 waves, wave w owns local c-tiles {2w, 2w+1} ----
  for (int h = 0; h < 2; ++h) {
    if (h == 1) {
      // restage XT with c 128..255 (all threads)
      if (use_xf) {
        for (int e = tid; e < K_ * 32; e += 256) {
          int j = e >> 5, qq = e & 31;
          int s = idxr[j];
          float4 v = *(const float4*)(xfb + (size_t)s * C_ + 128 + qq * 4);
          int c = qq * 4;
          XT[(c * 160 + j) ^ ((c & 7) << 3)] = f2bf(v.x);
          XT[((c + 1) * 160 + j) ^ (((c + 1) & 7) << 3)] = f2bf(v.y);
          XT[((c + 2) * 160 + j) ^ (((c + 2) & 7) << 3)] = f2bf(v.z);
          XT[((c + 3) * 160 + j) ^ (((c + 3) & 7) << 3)] = f2bf(v.w);
        }
      } else {
        for (int e = tid; e < 128 * K_; e += 256) {
          int c = e / K_, j = e % K_;
          XT[(c * 160 + j) ^ ((c & 7) << 3)] =
              f2bf(in[((size_t)b * C_ + 128 + c) * S_ + idxr[j]]);
        }
      }
      __syncthreads();
    }
    f32x4 o[9][2];
#pragma unroll
    for (int it = 0; it < 9; ++it)
#pragma unroll
      for (int u = 0; u < 2; ++u) o[it][u] = (f32x4){0.f, 0.f, 0.f, 0.f};
    int ctb = w * 2;
    for (int kt = 0; kt < 5; ++kt) {
      int j0 = kt * 32 + lg * 8;
      bf16x8 pa[9], vb[2];
#pragma unroll
      for (int it = 0; it < 9; ++it)
        pa[it] = *(const bf16x8*)&Ps[(it * 16 + lr) * 168 + j0];
#pragma unroll
      for (int u = 0; u < 2; ++u) {
        int cr = (ctb + u) * 16 + lr;
        vb[u] = *(const bf16x8*)&XT[(cr * 160 + j0) ^ ((cr & 7) << 3)];
      }
#pragma unroll
      for (int it = 0; it < 9; ++it)
#pragma unroll
        for (int u = 0; u < 2; ++u) o[it][u] = MFMA(pa[it], vb[u], o[it][u]);
    }
    // ---- scatter outputs ----
#pragma unroll
    for (int it = 0; it < 9; ++it)
#pragma unroll
      for (int u = 0; u < 2; ++u) {
        int cg = h * 128 + (ctb + u) * 16 + lr;
#pragma unroll
        for (int rr = 0; rr < 4; ++rr) {
          int i = it * 16 + lg * 4 + rr;
          int s = idxr[i];
          float val = o[it][u][rr];
          if (path_a)
            outacc[(((size_t)(b * A_ + a)) * S_ + s) * C_ + cg] = val;
          else
            atomicAdd(&out[((size_t)b * S_ + s) * C_ + cg], val * 0.25f);
        }
      }
    if (h == 0) __syncthreads();
  }
}

// ---------- average over rounds ----------
__global__ __launch_bounds__(256) void reduce_kernel(const float* __restrict__ acc,
                                                     float* __restrict__ out) {
  size_t i = (size_t)blockIdx.x * 256 + threadIdx.x;
  size_t n4 = (size_t)B_ * S_ * C_ / 4;
  if (i >= n4) return;
  size_t f = i * 4;
  size_t per_b = (size_t)S_ * C_;
  size_t b = f / per_b, o = f - b * per_b;
  const float* base = acc + (b * A_) * per_b + o;
  float4 v0 = *(const float4*)(base);
  float4 v1 = *(const float4*)(base + per_b);
  float4 v2 = *(const float4*)(base + 2 * per_b);
  float4 v3 = *(const float4*)(base + 3 * per_b);
  float4 rv = make_float4((v0.x + v1.x + v2.x + v3.x) * 0.25f,
                          (v0.y + v1.y + v2.y + v3.y) * 0.25f,
                          (v0.z + v1.z + v2.z + v3.z) * 0.25f,
                          (v0.w + v1.w + v2.w + v3.w) * 0.25f);
  *(float4*)(out + f) = rv;
}

__global__ __launch_bounds__(256) void zero_kernel(float* __restrict__ out) {
  size_t i = (size_t)blockIdx.x * 256 + threadIdx.x;
  size_t n4 = (size_t)B_ * S_ * C_ / 4;
  if (i >= n4) return;
  *(float4*)(out + i * 4) = make_float4(0.f, 0.f, 0.f, 0.f);
}

extern "C" void kernel_launch(void* const* d_in, const int* in_sizes, int n_in,
                              void* d_out, int out_size, void* d_ws, size_t ws_size,
                              hipStream_t stream) {
  const float* in = (const float*)d_in[0];
  const float* RM = (const float*)d_in[1];
  float* out = (float*)d_out;
  const size_t r64_b = (size_t)A_ * C_ * 64 * 8;        //   0.5 MB
  const size_t key_b = (size_t)B_ * A_ * S_ * 8;        //   2.36 MB
  const size_t idx_b = (size_t)B_ * A_ * S_ * 4;        //   1.18 MB
  const size_t xf_b  = (size_t)B_ * S_ * C_ * 4;        //  75.5 MB
  const size_t acc_b = (size_t)B_ * A_ * S_ * C_ * 4;   // 302 MB
  char* ws = (char*)d_ws;
  size_t off = 0;
  double* R64 = (double*)(ws + off); off += r64_b;
  unsigned long long* keys = (unsigned long long*)(ws + off); off += key_b;
  int* idxs = (int*)(ws + off); off += idx_b;
  int use_xf = ws_size >= off + xf_b;
  float* xf = nullptr;
  if (use_xf) { xf = (float*)(ws + off); off += xf_b; }
  int path_a = ws_size >= off + acc_b;
  float* outacc = nullptr;
  if (path_a) { outacc = (float*)(ws + off); off += acc_b; }

  cvt_r_kernel<<<dim3((A_ * C_ * 64 + 255) / 256), 256, 0, stream>>>(RM, R64);
  if (use_xf)
    t_kernel<<<dim3(S_ / 32, C_ / 32, B_), 256, 0, stream>>>(in, xf);
  hash_kernel<<<dim3(B_ * A_ * (S_ / 256)), 256, 0, stream>>>(in, R64, keys);
  sort_kernel<<<dim3(B_ * A_), 1024, 0, stream>>>(keys, idxs);
  size_t n4 = (size_t)B_ * S_ * C_ / 4;
  int rb = (int)((n4 + 255) / 256);
  if (!path_a) zero_kernel<<<dim3(rb), 256, 0, stream>>>(out);
  attn_kernel<<<dim3(B_ * A_ * NB_), 256, 0, stream>>>(xf, in, idxs, outacc, out, use_xf, path_a);
  if (path_a) reduce_kernel<<<dim3(rb), 256, 0, stream>>>(outacc, out);
}

// Round 4
// 1144.379 us; speedup vs baseline: 3.2603x; 1.0376x over previous
//
#include <hip/hip_runtime.h>
#include <math.h>

#define B_ 8
#define C_ 256
#define S_ 9216
#define A_ 4
#define K_ 144
#define NB_ 64
#define MCH 16   // hash m-chunk per pass (acc = 32 VGPRs fp64)

typedef __bf16 bf16x8 __attribute__((ext_vector_type(8)));
typedef float f32x4 __attribute__((ext_vector_type(4)));
#define MFMA(a, b, c) __builtin_amdgcn_mfma_f32_16x16x32_bf16(a, b, c, 0, 0, 0)

// bf16 round-to-nearest-even
__device__ __forceinline__ unsigned short f2bf(float f) {
  unsigned int u = __float_as_uint(f);
  u = (u + 0x7FFFu + ((u >> 16) & 1u)) >> 16;
  return (unsigned short)u;
}

// ---------- transpose: xf[b][s][c] = in[b][c][s] ----------
__global__ __launch_bounds__(256) void t_kernel(const float* __restrict__ in,
                                                float* __restrict__ xf) {
  __shared__ float tile[32][33];
  int b = blockIdx.z;
  int c0 = blockIdx.y << 5, s0 = blockIdx.x << 5;
  int x = threadIdx.x & 31, y = threadIdx.x >> 5;  // 32 x 8
  const float* ip = in + ((size_t)b * C_ + c0 + y) * S_ + s0 + x;
#pragma unroll
  for (int k = 0; k < 32; k += 8) tile[y + k][x] = ip[(size_t)k * S_];
  __syncthreads();
  float* op = xf + ((size_t)b * S_ + s0 + y) * C_ + c0 + x;
#pragma unroll
  for (int k = 0; k < 32; k += 8) op[(size_t)k * C_] = tile[x][y + k];
}

// ---------- R fp32 -> fp64 once ----------
__global__ __launch_bounds__(256) void cvt_r_kernel(const float* __restrict__ RM,
                                                    double* __restrict__ R64) {
  int i = blockIdx.x * 256 + threadIdx.x;
  if (i < A_ * C_ * 64) R64[i] = (double)RM[i];
}

// ---------- hash: thread = (b,a,s); fp64 FMA with SGPR-resident R ----------
__global__ __launch_bounds__(256) void hash_kernel(const float* __restrict__ in,
                                                   const double* __restrict__ R64,
                                                   unsigned long long* __restrict__ keys) {
  int blk = blockIdx.x;  // (b, a, s-chunk)
  int chunk = blk % (S_ / 256);
  int a = (blk / (S_ / 256)) % A_;
  int b = blk / (S_ / 256) / A_;
  int s = chunk * 256 + threadIdx.x;
  const float* __restrict__ xb = in + (size_t)b * C_ * S_ + s;
  const double* __restrict__ Rb = R64 + (size_t)a * C_ * 64;
  double hmax = -1e300;
  for (int mp = 0; mp < 64; mp += MCH) {
    double acc[MCH];
#pragma unroll
    for (int i = 0; i < MCH; ++i) acc[i] = 0.0;
#pragma unroll 2
    for (int c = 0; c < C_; ++c) {
      double xv = (double)xb[(size_t)c * S_];
      const double* __restrict__ Rc = Rb + c * 64 + mp;  // wave-uniform -> s_load
#pragma unroll
      for (int i = 0; i < MCH; ++i) acc[i] = fma(xv, Rc[i], acc[i]);
    }
#pragma unroll
    for (int i = 0; i < MCH; ++i) hmax = hmax > acc[i] ? hmax : acc[i];
  }
  unsigned long long u = (unsigned long long)__double_as_longlong(hmax);
  unsigned long long mono = u ^ ((u >> 63) ? ~0ull : 0x8000000000000000ull);
  keys[((size_t)(b * A_ + a)) * S_ + s] = (~mono & ~0x3FFFull) | (unsigned long long)s;
}

// ---------- bitonic sort of 16384 uint64 keys in LDS, per (b,a) ----------
__global__ __launch_bounds__(1024) void sort_kernel(const unsigned long long* __restrict__ keys,
                                                    int* __restrict__ idxs) {
  __shared__ unsigned long long lk[16384];  // 128 KiB
  int tid = threadIdx.x;
  const unsigned long long* kb = keys + (size_t)blockIdx.x * S_;
  for (int i = tid; i < 16384; i += 1024) lk[i] = (i < S_) ? kb[i] : ~0ull;
  for (int k = 2; k <= 16384; k <<= 1)
    for (int j = k >> 1; j > 0; j >>= 1) {
      __syncthreads();
      for (int i = tid; i < 16384; i += 1024) {
        int l = i ^ j;
        if (l > i) {
          unsigned long long a = lk[i], bv = lk[l];
          bool sw = ((i & k) == 0) ? (a > bv) : (a < bv);
          if (sw) { lk[i] = bv; lk[l] = a; }
        }
      }
    }
  __syncthreads();
  int* ob = idxs + (size_t)blockIdx.x * S_;
  for (int i = tid; i < S_; i += 1024) ob[i] = (int)(lk[i] & 0x3FFFull);
}

// ---------- per-bucket MFMA attention (bf16 in, fp32 accum), 8 waves ----------
// LDS: Xh [144][256] bf16, swz ^((row&7)<<3) on ushort idx   -> 73728 B
//      XT [128][160] bf16 half-c transposed, swz ^((c&7)<<3) -> 40960 B
//      Ps [144][168] bf16 probs, cols 144..167 zeroed        -> 48384 B
// Roles: waves 0-5 QK (w0:{0,6} w1:{1,7} w2:{2,8} w3:{3} w4:{4} w5:{5}),
//        waves 6-7 stage XT half0 + zero pads. PV: wave w = c-tile w.
__global__ __launch_bounds__(512, 1) void attn_kernel(const float* __restrict__ xf,
                                                      const float* __restrict__ in,
                                                      const int* __restrict__ idxs,
                                                      float* __restrict__ outacc,
                                                      float* __restrict__ out,
                                                      int use_xf, int path_a) {
  __shared__ __align__(16) unsigned short Xh[K_ * 256];   // 73728 B
  __shared__ __align__(16) unsigned short XT[128 * 160];  // 40960 B
  __shared__ __align__(16) unsigned short Ps[K_ * 168];   // 48384 B
  int blk = blockIdx.x;
  int r = blk & 63, a = (blk >> 6) & 3, b = blk >> 8;
  int tid = threadIdx.x;
  int w = __builtin_amdgcn_readfirstlane(tid >> 6);  // 0..7
  int lane = tid & 63;
  int lr = lane & 15, lg = lane >> 4;
  const int* __restrict__ idxr = idxs + ((size_t)(b * A_ + a)) * S_ + r * K_;
  const float* __restrict__ xfb = xf + (size_t)b * S_ * C_;

  // ---- stage Xh (all 512 threads) ----
  if (use_xf) {
    for (int e = tid; e < K_ * 64; e += 512) {
      int i = e >> 6, q = (e & 63) << 2;
      int s = idxr[i];
      float4 v = *(const float4*)(xfb + (size_t)s * C_ + q);
      unsigned int lo = (unsigned int)f2bf(v.x) | ((unsigned int)f2bf(v.y) << 16);
      unsigned int hi = (unsigned int)f2bf(v.z) | ((unsigned int)f2bf(v.w) << 16);
      int idx = (i * 256 + q) ^ ((i & 7) << 3);
      *(uint2*)&Xh[idx] = make_uint2(lo, hi);
    }
  } else {
    for (int e = tid; e < K_ * C_; e += 512) {
      int i = e >> 8, c = e & 255;
      Xh[(i * 256 + c) ^ ((i & 7) << 3)] =
          f2bf(in[((size_t)b * C_ + c) * S_ + idxr[i]]);
    }
  }
  __syncthreads();

  if (w < 6) {
    // ---- QK^T: tile t0 = w, and t1 = w+6 if w < 3 ----
    int t0 = w, t1 = w + 6;
    bool do2 = (w < 3);
    f32x4 acc0[9], acc1[9];
#pragma unroll
    for (int jt = 0; jt < 9; ++jt) {
      acc0[jt] = (f32x4){0.f, 0.f, 0.f, 0.f};
      acc1[jt] = (f32x4){0.f, 0.f, 0.f, 0.f};
    }
    for (int kt = 0; kt < 8; ++kt) {
      int c0 = kt * 32 + lg * 8;
      bf16x8 fr[9];
#pragma unroll
      for (int jt = 0; jt < 9; ++jt) {
        int row = jt * 16 + lr;
        fr[jt] = *(const bf16x8*)&Xh[(row * 256 + c0) ^ ((row & 7) << 3)];
      }
#pragma unroll
      for (int jt = 0; jt < 9; ++jt) acc0[jt] = MFMA(fr[t0], fr[jt], acc0[jt]);
      if (do2) {
#pragma unroll
        for (int jt = 0; jt < 9; ++jt) acc1[jt] = MFMA(fr[t1], fr[jt], acc1[jt]);
      }
    }
    // ---- softmax rows of tile t (16 rows via lg*4+rr), reduce over lr ----
    for (int p = 0; p < (do2 ? 2 : 1); ++p) {
      f32x4* ac = p ? acc1 : acc0;
      int t = p ? t1 : t0;
#pragma unroll
      for (int rr = 0; rr < 4; ++rr) {
        float m = -1e30f;
#pragma unroll
        for (int jt = 0; jt < 9; ++jt) m = fmaxf(m, ac[jt][rr]);
        m = fmaxf(m, __shfl_xor(m, 1));
        m = fmaxf(m, __shfl_xor(m, 2));
        m = fmaxf(m, __shfl_xor(m, 4));
        m = fmaxf(m, __shfl_xor(m, 8));
        float sum = 0.f;
        float ev[9];
#pragma unroll
        for (int jt = 0; jt < 9; ++jt) {
          float e = __expf((ac[jt][rr] - m) * 0.0625f);
          ev[jt] = e;
          sum += e;
        }
        sum += __shfl_xor(sum, 1);
        sum += __shfl_xor(sum, 2);
        sum += __shfl_xor(sum, 4);
        sum += __shfl_xor(sum, 8);
        float inv = 1.0f / sum;
        int row_i = t * 16 + lg * 4 + rr;
#pragma unroll
        for (int jt = 0; jt < 9; ++jt)
          Ps[row_i * 168 + jt * 16 + lr] = f2bf(ev[jt] * inv);
      }
    }
  } else if (w == 6) {
    // ---- zero Ps pad cols + stage XT half0 (even it-pairs) ----
    for (int e = lane; e < K_ * 24; e += 64) {
      int i = e / 24, j = 144 + e % 24;
      Ps[i * 168 + j] = 0;
    }
    if (use_xf) {
      for (int it = 0; it < 72; it += 2) {
        int j = it * 2 + (lane >> 5), qq = lane & 31;
        int s = idxr[j];
        float4 v = *(const float4*)(xfb + (size_t)s * C_ + qq * 4);
        int c = qq * 4;
        XT[(c * 160 + j) ^ ((c & 7) << 3)] = f2bf(v.x);
        XT[((c + 1) * 160 + j) ^ (((c + 1) & 7) << 3)] = f2bf(v.y);
        XT[((c + 2) * 160 + j) ^ (((c + 2) & 7) << 3)] = f2bf(v.z);
        XT[((c + 3) * 160 + j) ^ (((c + 3) & 7) << 3)] = f2bf(v.w);
      }
    } else {
      for (int c = 0; c < 128; c += 2)
        for (int j = lane; j < K_; j += 64)
          XT[(c * 160 + j) ^ ((c & 7) << 3)] =
              f2bf(in[((size_t)b * C_ + c) * S_ + idxr[j]]);
    }
  } else {
    // ---- w == 7: zero XT pad rows + stage XT half0 (odd it-pairs) ----
    for (int e = lane; e < 128 * 16; e += 64) {
      int c = e >> 4, j = 144 + (e & 15);
      XT[(c * 160 + j) ^ ((c & 7) << 3)] = 0;
    }
    if (use_xf) {
      for (int it = 1; it < 72; it += 2) {
        int j = it * 2 + (lane >> 5), qq = lane & 31;
        int s = idxr[j];
        float4 v = *(const float4*)(xfb + (size_t)s * C_ + qq * 4);
        int c = qq * 4;
        XT[(c * 160 + j) ^ ((c & 7) << 3)] = f2bf(v.x);
        XT[((c + 1) * 160 + j) ^ (((c + 1) & 7) << 3)] = f2bf(v.y);
        XT[((c + 2) * 160 + j) ^ (((c + 2) & 7) << 3)] = f2bf(v.z);
        XT[((c + 3) * 160 + j) ^ (((c + 3) & 7) << 3)] = f2bf(v.w);
      }
    } else {
      for (int c = 1; c < 128; c += 2)
        for (int j = lane; j < K_; j += 64)
          XT[(c * 160 + j) ^ ((c & 7) << 3)] =
              f2bf(in[((size_t)b * C_ + c) * S_ + idxr[j]]);
    }
  }
  __syncthreads();

  // ---- PV over c-half h: wave w owns c-tile w of the half ----
  for (int h = 0; h < 2; ++h) {
    if (h == 1) {
      // restage XT with c 128..255 (all 512 threads)
      if (use_xf) {
        for (int e = tid; e < K_ * 32; e += 512) {
          int j = e >> 5, qq = e & 31;
          int s = idxr[j];
          float4 v = *(const float4*)(xfb + (size_t)s * C_ + 128 + qq * 4);
          int c = qq * 4;
          XT[(c * 160 + j) ^ ((c & 7) << 3)] = f2bf(v.x);
          XT[((c + 1) * 160 + j) ^ (((c + 1) & 7) << 3)] = f2bf(v.y);
          XT[((c + 2) * 160 + j) ^ (((c + 2) & 7) << 3)] = f2bf(v.z);
          XT[((c + 3) * 160 + j) ^ (((c + 3) & 7) << 3)] = f2bf(v.w);
        }
      } else {
        for (int e = tid; e < 128 * K_; e += 512) {
          int c = e / K_, j = e % K_;
          XT[(c * 160 + j) ^ ((c & 7) << 3)] =
              f2bf(in[((size_t)b * C_ + 128 + c) * S_ + idxr[j]]);
        }
      }
      __syncthreads();
    }
    f32x4 o[9];
#pragma unroll
    for (int it = 0; it < 9; ++it) o[it] = (f32x4){0.f, 0.f, 0.f, 0.f};
    for (int kt = 0; kt < 5; ++kt) {
      int j0 = kt * 32 + lg * 8;
      bf16x8 pa[9], vb;
#pragma unroll
      for (int it = 0; it < 9; ++it)
        pa[it] = *(const bf16x8*)&Ps[(it * 16 + lr) * 168 + j0];
      {
        int cr = w * 16 + lr;
        vb = *(const bf16x8*)&XT[(cr * 160 + j0) ^ ((cr & 7) << 3)];
      }
#pragma unroll
      for (int it = 0; it < 9; ++it) o[it] = MFMA(pa[it], vb, o[it]);
    }
    // ---- scatter outputs ----
#pragma unroll
    for (int it = 0; it < 9; ++it) {
      int cg = h * 128 + w * 16 + lr;
#pragma unroll
      for (int rr = 0; rr < 4; ++rr) {
        int i = it * 16 + lg * 4 + rr;
        int s = idxr[i];
        float val = o[it][rr];
        if (path_a)
          outacc[(((size_t)(b * A_ + a)) * S_ + s) * C_ + cg] = val;
        else
          atomicAdd(&out[((size_t)b * S_ + s) * C_ + cg], val * 0.25f);
      }
    }
    if (h == 0) __syncthreads();
  }
}

// ---------- average over rounds ----------
__global__ __launch_bounds__(256) void reduce_kernel(const float* __restrict__ acc,
                                                     float* __restrict__ out) {
  size_t i = (size_t)blockIdx.x * 256 + threadIdx.x;
  size_t n4 = (size_t)B_ * S_ * C_ / 4;
  if (i >= n4) return;
  size_t f = i * 4;
  size_t per_b = (size_t)S_ * C_;
  size_t b = f / per_b, o = f - b * per_b;
  const float* base = acc + (b * A_) * per_b + o;
  float4 v0 = *(const float4*)(base);
  float4 v1 = *(const float4*)(base + per_b);
  float4 v2 = *(const float4*)(base + 2 * per_b);
  float4 v3 = *(const float4*)(base + 3 * per_b);
  float4 rv = make_float4((v0.x + v1.x + v2.x + v3.x) * 0.25f,
                          (v0.y + v1.y + v2.y + v3.y) * 0.25f,
                          (v0.z + v1.z + v2.z + v3.z) * 0.25f,
                          (v0.w + v1.w + v2.w + v3.w) * 0.25f);
  *(float4*)(out + f) = rv;
}

__global__ __launch_bounds__(256) void zero_kernel(float* __restrict__ out) {
  size_t i = (size_t)blockIdx.x * 256 + threadIdx.x;
  size_t n4 = (size_t)B_ * S_ * C_ / 4;
  if (i >= n4) return;
  *(float4*)(out + i * 4) = make_float4(0.f, 0.f, 0.f, 0.f);
}

extern "C" void kernel_launch(void* const* d_in, const int* in_sizes, int n_in,
                              void* d_out, int out_size, void* d_ws, size_t ws_size,
                              hipStream_t stream) {
  const float* in = (const float*)d_in[0];
  const float* RM = (const float*)d_in[1];
  float* out = (float*)d_out;
  const size_t r64_b = (size_t)A_ * C_ * 64 * 8;        //   0.5 MB
  const size_t key_b = (size_t)B_ * A_ * S_ * 8;        //   2.36 MB
  const size_t idx_b = (size_t)B_ * A_ * S_ * 4;        //   1.18 MB
  const size_t xf_b  = (size_t)B_ * S_ * C_ * 4;        //  75.5 MB
  const size_t acc_b = (size_t)B_ * A_ * S_ * C_ * 4;   // 302 MB
  char* ws = (char*)d_ws;
  size_t off = 0;
  double* R64 = (double*)(ws + off); off += r64_b;
  unsigned long long* keys = (unsigned long long*)(ws + off); off += key_b;
  int* idxs = (int*)(ws + off); off += idx_b;
  int use_xf = ws_size >= off + xf_b;
  float* xf = nullptr;
  if (use_xf) { xf = (float*)(ws + off); off += xf_b; }
  int path_a = ws_size >= off + acc_b;
  float* outacc = nullptr;
  if (path_a) { outacc = (float*)(ws + off); off += acc_b; }

  cvt_r_kernel<<<dim3((A_ * C_ * 64 + 255) / 256), 256, 0, stream>>>(RM, R64);
  if (use_xf)
    t_kernel<<<dim3(S_ / 32, C_ / 32, B_), 256, 0, stream>>>(in, xf);
  hash_kernel<<<dim3(B_ * A_ * (S_ / 256)), 256, 0, stream>>>(in, R64, keys);
  sort_kernel<<<dim3(B_ * A_), 1024, 0, stream>>>(keys, idxs);
  size_t n4 = (size_t)B_ * S_ * C_ / 4;
  int rb = (int)((n4 + 255) / 256);
  if (!path_a) zero_kernel<<<dim3(rb), 256, 0, stream>>>(out);
  attn_kernel<<<dim3(B_ * A_ * NB_), 512, 0, stream>>>(xf, in, idxs, outacc, out, use_xf, path_a);
  if (path_a) reduce_kernel<<<dim3(rb), 256, 0, stream>>>(outacc, out);
}

// Round 5
// 961.779 us; speedup vs baseline: 3.8793x; 1.1899x over previous
//
#include <hip/hip_runtime.h>
#include <math.h>

#define B_ 8
#define C_ 256
#define S_ 9216
#define A_ 4
#define K_ 144
#define NB_ 64
#define MCH 16   // hash m-chunk per pass (acc = 32 VGPRs fp64)

typedef __bf16 bf16x8 __attribute__((ext_vector_type(8)));
typedef float f32x4 __attribute__((ext_vector_type(4)));
#define MFMA(a, b, c) __builtin_amdgcn_mfma_f32_16x16x32_bf16(a, b, c, 0, 0, 0)

// bf16 round-to-nearest-even
__device__ __forceinline__ unsigned short f2bf(float f) {
  unsigned int u = __float_as_uint(f);
  u = (u + 0x7FFFu + ((u >> 16) & 1u)) >> 16;
  return (unsigned short)u;
}
__device__ __forceinline__ float bf2f(unsigned short u) {
  return __uint_as_float(((unsigned int)u) << 16);
}

// ---------- transpose: xf[b][s][c] = in[b][c][s] ----------
__global__ __launch_bounds__(256) void t_kernel(const float* __restrict__ in,
                                                float* __restrict__ xf) {
  __shared__ float tile[32][33];
  int b = blockIdx.z;
  int c0 = blockIdx.y << 5, s0 = blockIdx.x << 5;
  int x = threadIdx.x & 31, y = threadIdx.x >> 5;  // 32 x 8
  const float* ip = in + ((size_t)b * C_ + c0 + y) * S_ + s0 + x;
#pragma unroll
  for (int k = 0; k < 32; k += 8) tile[y + k][x] = ip[(size_t)k * S_];
  __syncthreads();
  float* op = xf + ((size_t)b * S_ + s0 + y) * C_ + c0 + x;
#pragma unroll
  for (int k = 0; k < 32; k += 8) op[(size_t)k * C_] = tile[x][y + k];
}

// ---------- R fp32 -> fp64 once ----------
__global__ __launch_bounds__(256) void cvt_r_kernel(const float* __restrict__ RM,
                                                    double* __restrict__ R64) {
  int i = blockIdx.x * 256 + threadIdx.x;
  if (i < A_ * C_ * 64) R64[i] = (double)RM[i];
}

// ---------- hash: thread = (b,a,s); fp64 FMA with SGPR-resident R ----------
__global__ __launch_bounds__(256) void hash_kernel(const float* __restrict__ in,
                                                   const double* __restrict__ R64,
                                                   unsigned long long* __restrict__ keys) {
  int blk = blockIdx.x;  // (b, a, s-chunk)
  int chunk = blk % (S_ / 256);
  int a = (blk / (S_ / 256)) % A_;
  int b = blk / (S_ / 256) / A_;
  int s = chunk * 256 + threadIdx.x;
  const float* __restrict__ xb = in + (size_t)b * C_ * S_ + s;
  const double* __restrict__ Rb = R64 + (size_t)a * C_ * 64;
  double hmax = -1e300;
  for (int mp = 0; mp < 64; mp += MCH) {
    double acc[MCH];
#pragma unroll
    for (int i = 0; i < MCH; ++i) acc[i] = 0.0;
#pragma unroll 2
    for (int c = 0; c < C_; ++c) {
      double xv = (double)xb[(size_t)c * S_];
      const double* __restrict__ Rc = Rb + c * 64 + mp;  // wave-uniform -> s_load
#pragma unroll
      for (int i = 0; i < MCH; ++i) acc[i] = fma(xv, Rc[i], acc[i]);
    }
#pragma unroll
    for (int i = 0; i < MCH; ++i) hmax = hmax > acc[i] ? hmax : acc[i];
  }
  unsigned long long u = (unsigned long long)__double_as_longlong(hmax);
  unsigned long long mono = u ^ ((u >> 63) ? ~0ull : 0x8000000000000000ull);
  keys[((size_t)(b * A_ + a)) * S_ + s] = (~mono & ~0x3FFFull) | (unsigned long long)s;
}

// ---------- bitonic sort of 16384 uint64 keys in LDS, per (b,a) ----------
__global__ __launch_bounds__(1024) void sort_kernel(const unsigned long long* __restrict__ keys,
                                                    int* __restrict__ idxs) {
  __shared__ unsigned long long lk[16384];  // 128 KiB
  int tid = threadIdx.x;
  const unsigned long long* kb = keys + (size_t)blockIdx.x * S_;
  for (int i = tid; i < 16384; i += 1024) lk[i] = (i < S_) ? kb[i] : ~0ull;
  for (int k = 2; k <= 16384; k <<= 1)
    for (int j = k >> 1; j > 0; j >>= 1) {
      __syncthreads();
      for (int i = tid; i < 16384; i += 1024) {
        int l = i ^ j;
        if (l > i) {
          unsigned long long a = lk[i], bv = lk[l];
          bool sw = ((i & k) == 0) ? (a > bv) : (a < bv);
          if (sw) { lk[i] = bv; lk[l] = a; }
        }
      }
    }
  __syncthreads();
  int* ob = idxs + (size_t)blockIdx.x * S_;
  for (int i = tid; i < S_; i += 1024) ob[i] = (int)(lk[i] & 0x3FFFull);
}

// ---------- per-bucket MFMA attention, swapped-QK, 8 waves, 2 blocks/CU ----------
// LDS: R1 [144 j][128 c] bf16, c ^ ((j&7)<<3)   -> 36,864 B (X rows, one c-half)
//      R2 [128 c][144 j] bf16 (XT via v_perm)   -> 36,864 B
//      Ps8 [16 i][160 j] bf16 (tile-8 S/P)      ->  5,120 B
// Total 78,848 B -> 2 blocks/CU. Wave w owns i-tile w; tile 8 via Ps8.
__global__ __launch_bounds__(512, 4) void attn_kernel(const float* __restrict__ xf,
                                                      const float* __restrict__ in,
                                                      const int* __restrict__ idxs,
                                                      float* __restrict__ outacc,
                                                      float* __restrict__ out,
                                                      int use_xf, int path_a) {
  __shared__ __align__(16) unsigned short R1[K_ * 128];
  __shared__ __align__(16) unsigned short R2[128 * K_];
  __shared__ __align__(16) unsigned short Ps8[16 * 160];
  const int blk = blockIdx.x;
  const int r = blk & 63, a = (blk >> 6) & 3, b = blk >> 8;
  const int tid = threadIdx.x;
  const int w = __builtin_amdgcn_readfirstlane(tid >> 6);  // 0..7
  const int lane = tid & 63, lr = lane & 15, lg = lane >> 4;
  const int* __restrict__ idxr = idxs + ((size_t)(b * A_ + a)) * S_ + r * K_;
  const float* __restrict__ xfb = xf + (size_t)b * S_ * C_;
  const float scale = 0.0625f;  // 1/sqrt(256)

  // ---- stage one c-half of X rows into R1 ----
  auto stage = [&](int ch) {
    if (use_xf) {
      for (int e = tid; e < K_ * 16; e += 512) {
        int i = e >> 4, q8 = (e & 15) << 3;
        int s = idxr[i];
        const float* p = xfb + (size_t)s * C_ + ch * 128 + q8;
        float4 v0 = *(const float4*)p;
        float4 v1 = *(const float4*)(p + 4);
        uint4 d;
        d.x = (unsigned int)f2bf(v0.x) | ((unsigned int)f2bf(v0.y) << 16);
        d.y = (unsigned int)f2bf(v0.z) | ((unsigned int)f2bf(v0.w) << 16);
        d.z = (unsigned int)f2bf(v1.x) | ((unsigned int)f2bf(v1.y) << 16);
        d.w = (unsigned int)f2bf(v1.z) | ((unsigned int)f2bf(v1.w) << 16);
        *(uint4*)&R1[i * 128 + (q8 ^ ((i & 7) << 3))] = d;
      }
    } else {
      for (int e = tid; e < K_ * 128; e += 512) {
        int i = e >> 7, c = e & 127;
        R1[i * 128 + (c ^ ((i & 7) << 3))] =
            f2bf(in[((size_t)b * C_ + ch * 128 + c) * S_ + idxr[i]]);
      }
    }
  };

  // ---- R1 (X rows, c-half) -> R2 (XT) via per-thread 8x8 v_perm transpose ----
  auto transp = [&]() {
    int L = (tid & 7) | ((tid >> 8) << 3);  // c-block 0..15 (low bits in lane)
    int jb = (tid >> 3) & 31;               // j-block 0..17 (low bits in lane)
    if (jb < 18) {
      uint4 rv[8];
#pragma unroll
      for (int rr = 0; rr < 8; ++rr)
        rv[rr] = *(const uint4*)&R1[(jb * 8 + rr) * 128 + ((L * 8) ^ (rr << 3))];
#pragma unroll
      for (int cc = 0; cc < 8; ++cc) {
        unsigned int sel = (cc & 1) ? 0x07060302u : 0x05040100u;
        uint4 d;
        unsigned int* dd = (unsigned int*)&d;
#pragma unroll
        for (int q = 0; q < 4; ++q) {
          unsigned int lo = ((const unsigned int*)&rv[2 * q])[cc >> 1];
          unsigned int hi = ((const unsigned int*)&rv[2 * q + 1])[cc >> 1];
          dd[q] = __builtin_amdgcn_perm(hi, lo, sel);
        }
        *(uint4*)&R2[(L * 8 + cc) * K_ + jb * 8] = d;
      }
    }
  };

  // zero Ps8 (incl. pad cols 144..159, which stay zero)
  for (int e = tid; e < 16 * 160 / 2; e += 512) ((unsigned int*)Ps8)[e] = 0u;
  stage(0);
  __syncthreads();

  // ---- QK^T (swapped): acc[jt] = S[j in tile jt][i in tile w] ----
  f32x4 acc[9], acc8, acc8b;
#pragma unroll
  for (int jt = 0; jt < 9; ++jt) acc[jt] = (f32x4){0.f, 0.f, 0.f, 0.f};
  acc8 = (f32x4){0.f, 0.f, 0.f, 0.f};
  acc8b = (f32x4){0.f, 0.f, 0.f, 0.f};
  auto qk_half = [&]() {
    for (int kt = 0; kt < 4; ++kt) {
      int c0 = kt * 32 + lg * 8;
      int sw = c0 ^ ((lr & 7) << 3);
      bf16x8 fr[9];
#pragma unroll
      for (int jt = 0; jt < 9; ++jt)
        fr[jt] = *(const bf16x8*)&R1[(jt * 16 + lr) * 128 + sw];
      bf16x8 bT = *(const bf16x8*)&R1[(w * 16 + lr) * 128 + sw];
#pragma unroll
      for (int jt = 0; jt < 9; ++jt) acc[jt] = MFMA(fr[jt], bT, acc[jt]);
      acc8 = MFMA(bT, fr[8], acc8);           // j in tile w, i in tile 8
      if (w == 0) acc8b = MFMA(fr[8], fr[8], acc8b);
    }
  };
  qk_half();
  transp();            // R2 <- XT(c-half 0); safe: only reads R1, writes R2
  __syncthreads();
  stage(1);            // R1 <- c-half 1
  __syncthreads();
  qk_half();           // accumulate c 128..255

  // ---- tile-8 raw scores -> Ps8 ----
#pragma unroll
  for (int mm = 0; mm < 4; ++mm)
    Ps8[lr * 160 + (w * 16 + lg * 4 + mm)] = f2bf(acc8[mm]);
  if (w == 0) {
#pragma unroll
    for (int mm = 0; mm < 4; ++mm)
      Ps8[lr * 160 + (128 + lg * 4 + mm)] = f2bf(acc8b[mm]);
  }

  // ---- own-tile softmax fully in registers (i = w*16 + lr) ----
  float mx = -1e30f;
#pragma unroll
  for (int jt = 0; jt < 9; ++jt)
#pragma unroll
    for (int mm = 0; mm < 4; ++mm) mx = fmaxf(mx, acc[jt][mm]);
  mx = fmaxf(mx, __shfl_xor(mx, 16));
  mx = fmaxf(mx, __shfl_xor(mx, 32));
  float sum = 0.f;
#pragma unroll
  for (int jt = 0; jt < 9; ++jt)
#pragma unroll
    for (int mm = 0; mm < 4; ++mm) {
      float e = __expf((acc[jt][mm] - mx) * scale);
      acc[jt][mm] = e;
      sum += e;
    }
  sum += __shfl_xor(sum, 16);
  sum += __shfl_xor(sum, 32);
  float inv = 1.0f / sum;
  unsigned int pk[18];
#pragma unroll
  for (int jt = 0; jt < 9; ++jt) {
    pk[2 * jt] = (unsigned int)f2bf(acc[jt][0] * inv) |
                 ((unsigned int)f2bf(acc[jt][1] * inv) << 16);
    pk[2 * jt + 1] = (unsigned int)f2bf(acc[jt][2] * inv) |
                     ((unsigned int)f2bf(acc[jt][3] * inv) << 16);
  }

  // ---- build PV A-frags from registers (8 shfl per K-step) ----
  const int src1 = lr + 16 * ((2 * lg) & 3);
  const int src2 = lr + 16 * ((2 * lg + 1) & 3);
  const int hi8 = lg >> 1;
  bf16x8 pa[5];
#pragma unroll
  for (int kt = 0; kt < 5; ++kt) {
    const int jt0 = (kt < 4) ? 2 * kt : 7;
    unsigned int d0a = __shfl(pk[2 * jt0], src1), d0b = __shfl(pk[2 * jt0 + 2], src1);
    unsigned int d1a = __shfl(pk[2 * jt0 + 1], src1), d1b = __shfl(pk[2 * jt0 + 3], src1);
    unsigned int d2a = __shfl(pk[2 * jt0], src2), d2b = __shfl(pk[2 * jt0 + 2], src2);
    unsigned int d3a = __shfl(pk[2 * jt0 + 1], src2), d3b = __shfl(pk[2 * jt0 + 3], src2);
    uint4 d;
    d.x = hi8 ? d0b : d0a;
    d.y = hi8 ? d1b : d1a;
    d.z = hi8 ? d2b : d2a;
    d.w = hi8 ? d3b : d3a;
    if (kt == 4 && lg < 2) d = make_uint4(0u, 0u, 0u, 0u);  // j 112..127 already in kt3
    pa[kt] = *(bf16x8*)&d;
  }
  __syncthreads();

  // ---- tile-8 softmax (wave w: rows 2w, 2w+1 of Ps8) ----
  for (int rr = 0; rr < 2; ++rr) {
    int row = 2 * w + rr;
    float x0 = bf2f(Ps8[row * 160 + lane]);
    float x1 = bf2f(Ps8[row * 160 + 64 + lane]);
    float x2 = (lane < 16) ? bf2f(Ps8[row * 160 + 128 + lane]) : -1e30f;
    float m8 = fmaxf(fmaxf(x0, x1), x2);
    for (int off = 32; off; off >>= 1) m8 = fmaxf(m8, __shfl_xor(m8, off));
    float e0 = __expf((x0 - m8) * scale), e1 = __expf((x1 - m8) * scale);
    float e2 = (lane < 16) ? __expf((x2 - m8) * scale) : 0.f;
    float s8 = e0 + e1 + e2;
    for (int off = 32; off; off >>= 1) s8 += __shfl_xor(s8, off);
    float i8 = 1.0f / s8;
    Ps8[row * 160 + lane] = f2bf(e0 * i8);
    Ps8[row * 160 + 64 + lane] = f2bf(e1 * i8);
    if (lane < 16) Ps8[row * 160 + 128 + lane] = f2bf(e2 * i8);
  }
  __syncthreads();

  // ---- PV per c-half: O[i][c] = sum_j P[i][j] X[j][c] ----
  auto pv_half = [&](int h) {
    f32x4 o[8], o8;
#pragma unroll
    for (int ct = 0; ct < 8; ++ct) o[ct] = (f32x4){0.f, 0.f, 0.f, 0.f};
    o8 = (f32x4){0.f, 0.f, 0.f, 0.f};
#pragma unroll
    for (int kt = 0; kt < 5; ++kt) {
      int J0 = (kt < 4) ? kt * 32 : 112;
      int j8 = (kt < 4) ? (J0 + lg * 8) : ((lg < 2) ? (144 + lg * 8) : (112 + lg * 8));
      bf16x8 pa8 = *(const bf16x8*)&Ps8[lr * 160 + j8];
#pragma unroll
      for (int ct = 0; ct < 8; ++ct) {
        bf16x8 vb = *(const bf16x8*)&R2[(ct * 16 + lr) * K_ + J0 + lg * 8];
        o[ct] = MFMA(pa[kt], vb, o[ct]);
        if (ct == w) o8 = MFMA(pa8, vb, o8);
      }
    }
    // scatter: own tile rows i = w*16 + lg*4 + rr; tile-8 rows 128 + lg*4 + rr
#pragma unroll
    for (int ct = 0; ct < 8; ++ct) {
      int cg = h * 128 + ct * 16 + lr;
#pragma unroll
      for (int rr = 0; rr < 4; ++rr) {
        int s = idxr[w * 16 + lg * 4 + rr];
        float val = o[ct][rr];
        if (path_a)
          outacc[(((size_t)(b * A_ + a)) * S_ + s) * C_ + cg] = val;
        else
          atomicAdd(&out[((size_t)b * S_ + s) * C_ + cg], val * 0.25f);
      }
    }
    int cg8 = h * 128 + w * 16 + lr;
#pragma unroll
    for (int rr = 0; rr < 4; ++rr) {
      int s = idxr[128 + lg * 4 + rr];
      float val = o8[rr];
      if (path_a)
        outacc[(((size_t)(b * A_ + a)) * S_ + s) * C_ + cg8] = val;
      else
        atomicAdd(&out[((size_t)b * S_ + s) * C_ + cg8], val * 0.25f);
    }
  };

  pv_half(0);          // R2 holds XT(c-half 0)
  __syncthreads();
  transp();            // R2 <- XT(c-half 1) from R1 (still holds c-half 1)
  __syncthreads();
  pv_half(1);
}

// ---------- average over rounds ----------
__global__ __launch_bounds__(256) void reduce_kernel(const float* __restrict__ acc,
                                                     float* __restrict__ out) {
  size_t i = (size_t)blockIdx.x * 256 + threadIdx.x;
  size_t n4 = (size_t)B_ * S_ * C_ / 4;
  if (i >= n4) return;
  size_t f = i * 4;
  size_t per_b = (size_t)S_ * C_;
  size_t b = f / per_b, o = f - b * per_b;
  const float* base = acc + (b * A_) * per_b + o;
  float4 v0 = *(const float4*)(base);
  float4 v1 = *(const float4*)(base + per_b);
  float4 v2 = *(const float4*)(base + 2 * per_b);
  float4 v3 = *(const float4*)(base + 3 * per_b);
  float4 rv = make_float4((v0.x + v1.x + v2.x + v3.x) * 0.25f,
                          (v0.y + v1.y + v2.y + v3.y) * 0.25f,
                          (v0.z + v1.z + v2.z + v3.z) * 0.25f,
                          (v0.w + v1.w + v2.w + v3.w) * 0.25f);
  *(float4*)(out + f) = rv;
}

__global__ __launch_bounds__(256) void zero_kernel(float* __restrict__ out) {
  size_t i = (size_t)blockIdx.x * 256 + threadIdx.x;
  size_t n4 = (size_t)B_ * S_ * C_ / 4;
  if (i >= n4) return;
  *(float4*)(out + i * 4) = make_float4(0.f, 0.f, 0.f, 0.f);
}

extern "C" void kernel_launch(void* const* d_in, const int* in_sizes, int n_in,
                              void* d_out, int out_size, void* d_ws, size_t ws_size,
                              hipStream_t stream) {
  const float* in = (const float*)d_in[0];
  const float* RM = (const float*)d_in[1];
  float* out = (float*)d_out;
  const size_t r64_b = (size_t)A_ * C_ * 64 * 8;        //   0.5 MB
  const size_t key_b = (size_t)B_ * A_ * S_ * 8;        //   2.36 MB
  const size_t idx_b = (size_t)B_ * A_ * S_ * 4;        //   1.18 MB
  const size_t xf_b  = (size_t)B_ * S_ * C_ * 4;        //  75.5 MB
  const size_t acc_b = (size_t)B_ * A_ * S_ * C_ * 4;   // 302 MB
  char* ws = (char*)d_ws;
  size_t off = 0;
  double* R64 = (double*)(ws + off); off += r64_b;
  unsigned long long* keys = (unsigned long long*)(ws + off); off += key_b;
  int* idxs = (int*)(ws + off); off += idx_b;
  int use_xf = ws_size >= off + xf_b;
  float* xf = nullptr;
  if (use_xf) { xf = (float*)(ws + off); off += xf_b; }
  int path_a = ws_size >= off + acc_b;
  float* outacc = nullptr;
  if (path_a) { outacc = (float*)(ws + off); off += acc_b; }

  cvt_r_kernel<<<dim3((A_ * C_ * 64 + 255) / 256), 256, 0, stream>>>(RM, R64);
  if (use_xf)
    t_kernel<<<dim3(S_ / 32, C_ / 32, B_), 256, 0, stream>>>(in, xf);
  hash_kernel<<<dim3(B_ * A_ * (S_ / 256)), 256, 0, stream>>>(in, R64, keys);
  sort_kernel<<<dim3(B_ * A_), 1024, 0, stream>>>(keys, idxs);
  size_t n4 = (size_t)B_ * S_ * C_ / 4;
  int rb = (int)((n4 + 255) / 256);
  if (!path_a) zero_kernel<<<dim3(rb), 256, 0, stream>>>(out);
  attn_kernel<<<dim3(B_ * A_ * NB_), 512, 0, stream>>>(xf, in, idxs, outacc, out, use_xf, path_a);
  if (path_a) reduce_kernel<<<dim3(rb), 256, 0, stream>>>(outacc, out);
}